// Round 8
// baseline (140.775 us; speedup 1.0000x reference)
//
#include <hip/hip_runtime.h>
#include <stdint.h>

#define Bn 4
#define Cn 64
#define Sn 4096
#define Gn 32

typedef float v4f __attribute__((ext_vector_type(4)));
typedef short v8s __attribute__((ext_vector_type(8)));
typedef short v4s __attribute__((ext_vector_type(4)));

#define MFMA16(a,b,c) __builtin_amdgcn_mfma_f32_16x16x32_bf16((a),(b),(c),0,0,0)

__device__ __forceinline__ float bf2f(uint16_t u){
  union { uint32_t i; float f; } x; x.i = ((uint32_t)u) << 16; return x.f;
}
__device__ __forceinline__ uint16_t f2bf(float f){
  union { float f; uint32_t i; } x; x.f = f;
  uint32_t r = x.i + 0x7fffu + ((x.i >> 16) & 1u);
  return (uint16_t)(r >> 16);
}
__device__ __forceinline__ uint16_t f2bf_trunc(float f){
  union { float f; uint32_t i; } x; x.f = f;
  return (uint16_t)(x.i >> 16);
}
__device__ __forceinline__ v8s pack8(float4 a, float4 b){
  v8s r;
  r[0]=(short)f2bf(a.x); r[1]=(short)f2bf(a.y); r[2]=(short)f2bf(a.z); r[3]=(short)f2bf(a.w);
  r[4]=(short)f2bf(b.x); r[5]=(short)f2bf(b.y); r[6]=(short)f2bf(b.z); r[7]=(short)f2bf(b.w);
  return r;
}

// ---------------- kernel 1: GroupNorm stats (mean, rstd) ----------------
__global__ __launch_bounds__(256) void gn_stats(const float* __restrict__ x,
                                                float* __restrict__ stats)
{
  const int tid = threadIdx.x;
  const float* base = x + (size_t)blockIdx.x * 8192;
  float sum = 0.f, sq = 0.f;
  #pragma unroll
  for (int i = 0; i < 8; ++i) {
    float4 v = *(const float4*)(base + ((i << 8) + tid)*4);
    sum += v.x + v.y + v.z + v.w;
    sq  += v.x*v.x + v.y*v.y + v.z*v.z + v.w*v.w;
  }
  #pragma unroll
  for (int off = 1; off < 64; off <<= 1) {
    sum += __shfl_xor(sum, off);
    sq  += __shfl_xor(sq, off);
  }
  __shared__ float red[8];
  const int w = tid >> 6;
  if ((tid & 63) == 0) { red[w] = sum; red[4+w] = sq; }
  __syncthreads();
  if (tid == 0) {
    float s = red[0]+red[1]+red[2]+red[3];
    float q = red[4]+red[5]+red[6]+red[7];
    float mean = s * (1.f/8192.f);
    float var  = q * (1.f/8192.f) - mean*mean;
    stats[blockIdx.x]       = mean;
    stats[128 + blockIdx.x] = rsqrtf(fmaxf(var, 0.f) + 1e-5f);
  }
}

// ---------------- kernel 2: normalize + QKV projection (16-row tiles) --------
// grid 1024: bx = b*256 + st, s_base = st*16. Q,K out [b][s][c]; V out [b][c][s]
__global__ __launch_bounds__(256) void gn_qkv(
    const float* __restrict__ xg, const float* __restrict__ gamma,
    const float* __restrict__ beta,
    const float* __restrict__ wq, const float* __restrict__ bq,
    const float* __restrict__ wk, const float* __restrict__ bk,
    const float* __restrict__ wv, const float* __restrict__ bv,
    const float* __restrict__ stats,
    uint16_t* __restrict__ Qg, uint16_t* __restrict__ Kg, uint16_t* __restrict__ Vg)
{
  __shared__ uint16_t Hs[16*68];   // [s][c] bf16, pad 68
  const int tid  = threadIdx.x;
  const int w    = tid >> 6;
  const int lane = tid & 63;
  const int l15  = lane & 15;
  const int quad = lane >> 4;
  const int b      = blockIdx.x >> 8;
  const int s_base = (blockIdx.x & 255) << 4;

  {
    const int c = lane;
    const int g = c >> 1;
    const float mean = stats[b*Gn + g];
    const float rstd = stats[128 + b*Gn + g];
    const float ga = gamma[c], be = beta[c];
    float4 v = *(const float4*)(xg + ((size_t)b*Cn + c)*Sn + s_base + (w << 2));
    const int r0 = w << 2;
    Hs[(r0+0)*68 + c] = f2bf((v.x - mean)*rstd*ga + be);
    Hs[(r0+1)*68 + c] = f2bf((v.y - mean)*rstd*ga + be);
    Hs[(r0+2)*68 + c] = f2bf((v.z - mean)*rstd*ga + be);
    Hs[(r0+3)*68 + c] = f2bf((v.w - mean)*rstd*ga + be);
  }
  __syncthreads();

  v8s bh0 = *(const v8s*)(Hs + l15*68 + (quad << 3));
  v8s bh1 = *(const v8s*)(Hs + l15*68 + 32 + (quad << 3));

  #pragma unroll
  for (int t = 0; t < 3; ++t) {
    const int ot   = w*3 + t;          // 0..11 across the 4 waves
    const int wsel = ot >> 2;
    const int o16  = (ot & 3) << 4;
    const float* Wsel = (wsel == 0) ? wq : (wsel == 1) ? wk : wv;
    const float* Bsel = (wsel == 0) ? bq : (wsel == 1) ? bk : bv;
    const float* Wr = Wsel + (o16 + l15)*64 + (quad << 3);
    v8s a0 = pack8(*(const float4*)(Wr),      *(const float4*)(Wr + 4));
    v8s a1 = pack8(*(const float4*)(Wr + 32), *(const float4*)(Wr + 36));
    v4f d = (v4f){0.f,0.f,0.f,0.f};
    d = MFMA16(a0, bh0, d);
    d = MFMA16(a1, bh1, d);
    const int s = s_base + l15;
    if (wsel <= 1) {
      v4s qv;
      #pragma unroll
      for (int r = 0; r < 4; ++r)
        qv[r] = (short)f2bf(d[r] + Bsel[o16 + (quad << 2) + r]);
      uint16_t* dst = (wsel == 0 ? Qg : Kg) + ((size_t)b*Sn + s)*64 + o16 + (quad << 2);
      *(v4s*)dst = qv;
    } else {
      #pragma unroll
      for (int r = 0; r < 4; ++r) {
        const int o = o16 + (quad << 2) + r;
        Vg[((size_t)b*Cn + o)*Sn + s] = f2bf(d[r] + Bsel[o]);
      }
    }
  }
}

// ---------------- kernel 3: attention, split-K x4, 64 q/block, frag-major ----
// grid 1024: bx = ((b*64 + qt)*4 + split); 4 waves x 16 queries.
// K/V staged in frag-major LDS (read = region + lane*16B, conflict-free);
// register prefetch of tile kt+1 overlaps compute; 4 blocks/CU.
__global__ __launch_bounds__(256) void attn_split(
    const uint16_t* __restrict__ Qg, const uint16_t* __restrict__ Kg,
    const uint16_t* __restrict__ Vg,
    uint16_t* __restrict__ Opart, float* __restrict__ lpart)
{
  __shared__ uint16_t KT[4096];        // frag-major K tile (8 KB)
  __shared__ uint16_t VT[4096];        // frag-major V tile (8 KB)
  __shared__ uint16_t Ps[4][16*68];    // per-wave P scratch (pad 68)

  const int tid  = threadIdx.x;
  const int w    = tid >> 6;
  const int lane = tid & 63;
  const int l15  = lane & 15;
  const int quad = lane >> 4;
  const int bx    = blockIdx.x;
  const int split = bx & 3;
  const int qt    = (bx >> 2) & 63;
  const int b     = bx >> 8;
  const int i_base = qt << 6;
  const int j0     = split << 10;

  const uint16_t* Qb = Qg + ((size_t)b*Sn + i_base)*64;
  const uint16_t* Kb = Kg + (size_t)b*Sn*64;
  const uint16_t* Vb = Vg + (size_t)b*Cn*Sn;

  // Q A-fragments (once): wave w owns queries [w*16, +16)
  const int arow = (w << 4) + l15;
  v8s aq0 = *(const v8s*)(Qb + (size_t)arow*64 + (quad << 3));
  v8s aq1 = *(const v8s*)(Qb + (size_t)arow*64 + 32 + (quad << 3));

  // staging decode: 16B slot s = (n*2+h)*64 + lane'; thread covers s=tid, tid+256
  const int h0 = (tid >> 6) & 1, nA = tid >> 7, nB = nA + 2;
  const int qq = (tid >> 4) & 3, ff = tid & 15;
  const int gcol = h0*32 + qq*8;       // channel/key offset within 64-wide slice

  { // stage tile 0
    *(v8s*)(KT + (tid << 3))       = *(const v8s*)(Kb + (size_t)(j0 + (nA << 4) + ff)*64 + gcol);
    *(v8s*)(KT + ((tid+256) << 3)) = *(const v8s*)(Kb + (size_t)(j0 + (nB << 4) + ff)*64 + gcol);
    *(v8s*)(VT + (tid << 3))       = *(const v8s*)(Vb + (size_t)((nA << 4) + ff)*Sn + j0 + gcol);
    *(v8s*)(VT + ((tid+256) << 3)) = *(const v8s*)(Vb + (size_t)((nB << 4) + ff)*Sn + j0 + gcol);
  }

  float lsum[4];
  v4f o_acc[4];
  #pragma unroll
  for (int r = 0; r < 4; ++r) { lsum[r] = 0.f; o_acc[r] = (v4f){0.f,0.f,0.f,0.f}; }

  __syncthreads();

  const float SC = 0.18033688011112042f;   // (1/sqrt(64)) * log2(e)
  uint16_t* Pw = Ps[w];

  for (int kt = 0; kt < 16; ++kt) {
    // prefetch next tile into registers (latency overlaps compute)
    v8s kpA, kpB, vpA, vpB;
    if (kt < 15) {
      const int jb = j0 + ((kt + 1) << 6);
      kpA = *(const v8s*)(Kb + (size_t)(jb + (nA << 4) + ff)*64 + gcol);
      kpB = *(const v8s*)(Kb + (size_t)(jb + (nB << 4) + ff)*64 + gcol);
      vpA = *(const v8s*)(Vb + (size_t)((nA << 4) + ff)*Sn + jb + gcol);
      vpB = *(const v8s*)(Vb + (size_t)((nB << 4) + ff)*Sn + jb + gcol);
    }

    // S = Q K^T : K B-frags frag-major (region + lane*16B)
    v4f s[4];
    #pragma unroll
    for (int n = 0; n < 4; ++n) {
      v8s kb0 = *(const v8s*)(KT + (((n << 1) + 0) << 9) + (lane << 3));
      v8s kb1 = *(const v8s*)(KT + (((n << 1) + 1) << 9) + (lane << 3));
      v4f acc = (v4f){0.f,0.f,0.f,0.f};
      acc = MFMA16(aq0, kb0, acc);
      acc = MFMA16(aq1, kb1, acc);
      s[n] = acc;
    }

    // fixed-max softmax numerator p = 2^(s*SC); l reduction deferred to end
    #pragma unroll
    for (int n = 0; n < 4; ++n)
      #pragma unroll
      for (int r = 0; r < 4; ++r) {
        const float pv = __builtin_amdgcn_exp2f(s[n][r]*SC);
        lsum[r] += pv;
        Pw[((quad << 2) + r)*68 + (n << 4) + l15] = f2bf_trunc(pv);
      }

    __asm__ volatile("" ::: "memory");   // P reads strictly after P writes

    v8s ap0 = *(const v8s*)(Pw + l15*68 + (quad << 3));
    v8s ap1 = *(const v8s*)(Pw + l15*68 + 32 + (quad << 3));

    // O += P V^T : V B-frags frag-major
    #pragma unroll
    for (int n = 0; n < 4; ++n) {
      v8s vb0 = *(const v8s*)(VT + (((n << 1) + 0) << 9) + (lane << 3));
      v8s vb1 = *(const v8s*)(VT + (((n << 1) + 1) << 9) + (lane << 3));
      v4f o = o_acc[n];
      o = MFMA16(ap0, vb0, o);
      o = MFMA16(ap1, vb1, o);
      o_acc[n] = o;
    }

    __syncthreads();            // all waves done reading KT/VT
    if (kt < 15) {
      *(v8s*)(KT + (tid << 3))       = kpA;
      *(v8s*)(KT + ((tid+256) << 3)) = kpB;
      *(v8s*)(VT + (tid << 3))       = vpA;
      *(v8s*)(VT + ((tid+256) << 3)) = vpB;
    }
    __syncthreads();            // writeback visible
  }

  // reduce l across the 16 lanes holding each row (once)
  #pragma unroll
  for (int r = 0; r < 4; ++r) {
    lsum[r] += __shfl_xor(lsum[r], 1);
    lsum[r] += __shfl_xor(lsum[r], 2);
    lsum[r] += __shfl_xor(lsum[r], 4);
    lsum[r] += __shfl_xor(lsum[r], 8);
  }

  uint16_t* Ob = Opart + (size_t)bx*4096 + (w << 4)*64;
  float*    lp = lpart + bx*64 + (w << 4);
  #pragma unroll
  for (int n = 0; n < 4; ++n)
    #pragma unroll
    for (int r = 0; r < 4; ++r)
      Ob[((quad << 2) + r)*64 + (n << 4) + l15] = f2bf(o_acc[n][r]);
  if (l15 == 0) {
    #pragma unroll
    for (int r = 0; r < 4; ++r) lp[(quad << 2) + r] = lsum[r];
  }
}

// ---------------- kernel 4: merge splits + projection + residual (16-row) ----
// grid 1024: bx = b*256 + st; s rows [st*16, +16). out[b][c][s] = x + Wp@A + bp
__global__ __launch_bounds__(256) void proj_res(
    const uint16_t* __restrict__ Opart, const float* __restrict__ lpart,
    const float* __restrict__ wp, const float* __restrict__ bp,
    const float* __restrict__ xg, float* __restrict__ out)
{
  __shared__ uint16_t As[16*68];   // merged attention subtile [s][c]
  const int tid  = threadIdx.x;
  const int w    = tid >> 6;
  const int lane = tid & 63;
  const int l15  = lane & 15;
  const int quad = lane >> 4;
  const int b      = blockIdx.x >> 8;
  const int st     = blockIdx.x & 255;
  const int qt     = st >> 2;
  const int sub    = st & 3;
  const int s_base = st << 4;

  const uint16_t* po = Opart + (size_t)((b*64 + qt)*4)*4096 + (sub << 4)*64;
  const float*    pl = lpart + ((b*64 + qt)*4)*64 + (sub << 4);

  { // merge 4 splits: thread t -> 4 elems, row = t>>4, col = (t&15)*4
    const int e = tid << 2, row = tid >> 4, col = (tid & 15) << 2;
    const float linv = 1.f / (pl[row] + pl[64+row] + pl[128+row] + pl[192+row]);
    float acc[4] = {0.f,0.f,0.f,0.f};
    #pragma unroll
    for (int sp = 0; sp < 4; ++sp) {
      v4s o = *(const v4s*)(po + sp*4096 + e);
      #pragma unroll
      for (int j = 0; j < 4; ++j) acc[j] += bf2f((uint16_t)o[j]);
    }
    v4s a;
    #pragma unroll
    for (int j = 0; j < 4; ++j) a[j] = (short)f2bf(acc[j]*linv);
    *(v4s*)(As + row*68 + col) = a;
  }
  __syncthreads();

  v8s ba0 = *(const v8s*)(As + l15*68 + (quad << 3));
  v8s ba1 = *(const v8s*)(As + l15*68 + 32 + (quad << 3));

  // wave w computes output channels [w*16, +16)
  const float* Wr = wp + ((w << 4) + l15)*64 + (quad << 3);
  v8s a0 = pack8(*(const float4*)(Wr),      *(const float4*)(Wr + 4));
  v8s a1 = pack8(*(const float4*)(Wr + 32), *(const float4*)(Wr + 36));
  v4f d = (v4f){0.f,0.f,0.f,0.f};
  d = MFMA16(a0, ba0, d);
  d = MFMA16(a1, ba1, d);
  const int s = s_base + l15;
  #pragma unroll
  for (int r = 0; r < 4; ++r) {
    const int o = (w << 4) + (quad << 2) + r;
    const size_t idx = ((size_t)b*Cn + o)*Sn + s;
    out[idx] = d[r] + bp[o] + xg[idx];
  }
}

extern "C" void kernel_launch(void* const* d_in, const int* in_sizes, int n_in,
                              void* d_out, int out_size, void* d_ws, size_t ws_size,
                              hipStream_t stream)
{
  const float* x     = (const float*)d_in[0];
  const float* gamma = (const float*)d_in[1];
  const float* beta  = (const float*)d_in[2];
  const float* wq    = (const float*)d_in[3];
  const float* bq    = (const float*)d_in[4];
  const float* wk    = (const float*)d_in[5];
  const float* bk    = (const float*)d_in[6];
  const float* wv    = (const float*)d_in[7];
  const float* bv    = (const float*)d_in[8];
  const float* wp    = (const float*)d_in[9];
  const float* bp    = (const float*)d_in[10];

  float*    stats = (float*)d_ws;                        // 256 floats
  uint16_t* Qg    = (uint16_t*)d_ws + 1024;              // [B][S][C] bf16 (2 MiB)
  uint16_t* Kg    = Qg + (size_t)Bn*Sn*Cn;               // [B][S][C]
  uint16_t* Vg    = Kg + (size_t)Bn*Sn*Cn;               // [B][C][S]
  uint16_t* Opart = Vg + (size_t)Bn*Sn*Cn;               // 1024 x 64 x 64 bf16 (8 MiB)
  float*    lpart = (float*)(Opart + (size_t)1024*4096); // 1024 x 64 f32 (256 KiB)
  float*    outp  = (float*)d_out;

  gn_stats  <<<128, 256, 0, stream>>>(x, stats);
  gn_qkv    <<<1024, 256, 0, stream>>>(x, gamma, beta, wq, bq, wk, bk, wv, bv,
                                       stats, Qg, Kg, Vg);
  attn_split<<<1024, 256, 0, stream>>>(Qg, Kg, Vg, Opart, lpart);
  proj_res  <<<1024, 256, 0, stream>>>(Opart, lpart, wp, bp, x, outp);
}

// Round 9
// 137.622 us; speedup vs baseline: 1.0229x; 1.0229x over previous
//
#include <hip/hip_runtime.h>
#include <stdint.h>

#define Bn 4
#define Cn 64
#define Sn 4096
#define Gn 32

typedef float v4f __attribute__((ext_vector_type(4)));
typedef short v8s __attribute__((ext_vector_type(8)));
typedef short v4s __attribute__((ext_vector_type(4)));

#define MFMA16(a,b,c) __builtin_amdgcn_mfma_f32_16x16x32_bf16((a),(b),(c),0,0,0)

__device__ __forceinline__ float bf2f(uint16_t u){
  union { uint32_t i; float f; } x; x.i = ((uint32_t)u) << 16; return x.f;
}
__device__ __forceinline__ uint16_t f2bf(float f){
  union { float f; uint32_t i; } x; x.f = f;
  uint32_t r = x.i + 0x7fffu + ((x.i >> 16) & 1u);
  return (uint16_t)(r >> 16);
}
__device__ __forceinline__ uint16_t f2bf_trunc(float f){
  union { float f; uint32_t i; } x; x.f = f;
  return (uint16_t)(x.i >> 16);
}
__device__ __forceinline__ v8s pack8(float4 a, float4 b){
  v8s r;
  r[0]=(short)f2bf(a.x); r[1]=(short)f2bf(a.y); r[2]=(short)f2bf(a.z); r[3]=(short)f2bf(a.w);
  r[4]=(short)f2bf(b.x); r[5]=(short)f2bf(b.y); r[6]=(short)f2bf(b.z); r[7]=(short)f2bf(b.w);
  return r;
}

// ---------------- kernel 1: GroupNorm stats (mean, rstd) ----------------
__global__ __launch_bounds__(256) void gn_stats(const float* __restrict__ x,
                                                float* __restrict__ stats)
{
  const int tid = threadIdx.x;
  const float* base = x + (size_t)blockIdx.x * 8192;
  float sum = 0.f, sq = 0.f;
  #pragma unroll
  for (int i = 0; i < 8; ++i) {
    float4 v = *(const float4*)(base + ((i << 8) + tid)*4);
    sum += v.x + v.y + v.z + v.w;
    sq  += v.x*v.x + v.y*v.y + v.z*v.z + v.w*v.w;
  }
  #pragma unroll
  for (int off = 1; off < 64; off <<= 1) {
    sum += __shfl_xor(sum, off);
    sq  += __shfl_xor(sq, off);
  }
  __shared__ float red[8];
  const int w = tid >> 6;
  if ((tid & 63) == 0) { red[w] = sum; red[4+w] = sq; }
  __syncthreads();
  if (tid == 0) {
    float s = red[0]+red[1]+red[2]+red[3];
    float q = red[4]+red[5]+red[6]+red[7];
    float mean = s * (1.f/8192.f);
    float var  = q * (1.f/8192.f) - mean*mean;
    stats[blockIdx.x]       = mean;
    stats[128 + blockIdx.x] = rsqrtf(fmaxf(var, 0.f) + 1e-5f);
  }
}

// ---------------- kernel 2: normalize + QKV projection (16-row tiles) --------
// grid 1024: bx = b*256 + st, s_base = st*16. Q,K out [b][s][c]; V out [b][c][s]
__global__ __launch_bounds__(256) void gn_qkv(
    const float* __restrict__ xg, const float* __restrict__ gamma,
    const float* __restrict__ beta,
    const float* __restrict__ wq, const float* __restrict__ bq,
    const float* __restrict__ wk, const float* __restrict__ bk,
    const float* __restrict__ wv, const float* __restrict__ bv,
    const float* __restrict__ stats,
    uint16_t* __restrict__ Qg, uint16_t* __restrict__ Kg, uint16_t* __restrict__ Vg)
{
  __shared__ uint16_t Hs[16*68];   // [s][c] bf16, pad 68
  const int tid  = threadIdx.x;
  const int w    = tid >> 6;
  const int lane = tid & 63;
  const int l15  = lane & 15;
  const int quad = lane >> 4;
  const int b      = blockIdx.x >> 8;
  const int s_base = (blockIdx.x & 255) << 4;

  {
    const int c = lane;
    const int g = c >> 1;
    const float mean = stats[b*Gn + g];
    const float rstd = stats[128 + b*Gn + g];
    const float ga = gamma[c], be = beta[c];
    float4 v = *(const float4*)(xg + ((size_t)b*Cn + c)*Sn + s_base + (w << 2));
    const int r0 = w << 2;
    Hs[(r0+0)*68 + c] = f2bf((v.x - mean)*rstd*ga + be);
    Hs[(r0+1)*68 + c] = f2bf((v.y - mean)*rstd*ga + be);
    Hs[(r0+2)*68 + c] = f2bf((v.z - mean)*rstd*ga + be);
    Hs[(r0+3)*68 + c] = f2bf((v.w - mean)*rstd*ga + be);
  }
  __syncthreads();

  v8s bh0 = *(const v8s*)(Hs + l15*68 + (quad << 3));
  v8s bh1 = *(const v8s*)(Hs + l15*68 + 32 + (quad << 3));

  #pragma unroll
  for (int t = 0; t < 3; ++t) {
    const int ot   = w*3 + t;          // 0..11 across the 4 waves
    const int wsel = ot >> 2;
    const int o16  = (ot & 3) << 4;
    const float* Wsel = (wsel == 0) ? wq : (wsel == 1) ? wk : wv;
    const float* Bsel = (wsel == 0) ? bq : (wsel == 1) ? bk : bv;
    const float* Wr = Wsel + (o16 + l15)*64 + (quad << 3);
    v8s a0 = pack8(*(const float4*)(Wr),      *(const float4*)(Wr + 4));
    v8s a1 = pack8(*(const float4*)(Wr + 32), *(const float4*)(Wr + 36));
    v4f d = (v4f){0.f,0.f,0.f,0.f};
    d = MFMA16(a0, bh0, d);
    d = MFMA16(a1, bh1, d);
    const int s = s_base + l15;
    if (wsel <= 1) {
      v4s qv;
      #pragma unroll
      for (int r = 0; r < 4; ++r)
        qv[r] = (short)f2bf(d[r] + Bsel[o16 + (quad << 2) + r]);
      uint16_t* dst = (wsel == 0 ? Qg : Kg) + ((size_t)b*Sn + s)*64 + o16 + (quad << 2);
      *(v4s*)dst = qv;
    } else {
      #pragma unroll
      for (int r = 0; r < 4; ++r) {
        const int o = o16 + (quad << 2) + r;
        Vg[((size_t)b*Cn + o)*Sn + s] = f2bf(d[r] + Bsel[o]);
      }
    }
  }
}

// ---------------- kernel 3: attention, split-K x4, 2D wave split -------------
// grid 1024: bx = ((b*64 + qt)*4 + split); block = 64 queries, keys [split*1024,+1024).
// 4 waves = (qh, kh): wave owns 32 queries x 32 keys per 64-key tile.
// S^T = K Q^T (A=K from LDS frag-major, B=Q in regs) -> P rows contiguous ->
// b64 P writes + b128 P A-frag reads. PV: O += P V (A=P, B=V frag-major LDS).
// Each (split,kh) writes its own O/l partial; proj_res merges 8.
__global__ __launch_bounds__(256) void attn_split(
    const uint16_t* __restrict__ Qg, const uint16_t* __restrict__ Kg,
    const uint16_t* __restrict__ Vg,
    uint16_t* __restrict__ Opart, float* __restrict__ lpart)
{
  __shared__ uint16_t KT[4096];      // 8 regions x 512 elems: A-frag-major K tile
  __shared__ uint16_t VT[4096];      // 8 regions x 512 elems: B-frag-major V tile
  __shared__ uint16_t Ps[4][1280];   // per-wave P scratch [32 q][40]

  const int tid  = threadIdx.x;
  const int w    = tid >> 6;
  const int lane = tid & 63;
  const int l15  = lane & 15;
  const int quad = lane >> 4;
  const int qh   = w & 1;            // query half (32 q)
  const int kh   = w >> 1;           // key half (32 keys of each 64-tile)
  const int bx    = blockIdx.x;
  const int split = bx & 3;
  const int qt    = (bx >> 2) & 63;
  const int b     = bx >> 8;
  const int i_base = qt << 6;
  const int j0     = split << 10;

  const uint16_t* Qb = Qg + ((size_t)b*Sn + i_base)*64;
  const uint16_t* Kb = Kg + (size_t)b*Sn*64;
  const uint16_t* Vb = Vg + (size_t)b*Cn*Sn;

  // Q B-fragments in registers (once): queries qh*32 + t*16 + l15
  v8s qf[2][2];
  #pragma unroll
  for (int t = 0; t < 2; ++t) {
    const uint16_t* qr = Qb + (size_t)((qh << 5) + (t << 4) + l15)*64;
    qf[t][0] = *(const v8s*)(qr + (quad << 3));
    qf[t][1] = *(const v8s*)(qr + 32 + (quad << 3));
  }

  // staging decode: slot s (16B): row/c = (s>>7)*16 + (s&15), col/key = ((s>>6)&1)*32 + ((s>>4)&3)*8
  const int s0 = tid, s1 = tid + 256;
  const int kr0 = ((s0 >> 7) << 4) + (s0 & 15), kc0 = ((s0 >> 6) & 1)*32 + ((s0 >> 4) & 3)*8;
  const int kr1 = ((s1 >> 7) << 4) + (s1 & 15), kc1 = ((s1 >> 6) & 1)*32 + ((s1 >> 4) & 3)*8;

  { // stage tile 0
    *(v8s*)(KT + (s0 << 3)) = *(const v8s*)(Kb + (size_t)(j0 + kr0)*64 + kc0);
    *(v8s*)(KT + (s1 << 3)) = *(const v8s*)(Kb + (size_t)(j0 + kr1)*64 + kc1);
    *(v8s*)(VT + (s0 << 3)) = *(const v8s*)(Vb + (size_t)kr0*Sn + j0 + kc0);
    *(v8s*)(VT + (s1 << 3)) = *(const v8s*)(Vb + (size_t)kr1*Sn + j0 + kc1);
  }

  float lsum[2] = {0.f, 0.f};
  v4f o_acc[2][4];
  #pragma unroll
  for (int t = 0; t < 2; ++t)
    #pragma unroll
    for (int n = 0; n < 4; ++n) o_acc[t][n] = (v4f){0.f,0.f,0.f,0.f};

  __syncthreads();

  const float SC = 0.18033688011112042f;   // (1/sqrt(64)) * log2(e)
  uint16_t* Pw = Ps[w];

  for (int kt = 0; kt < 16; ++kt) {
    // prefetch next tile into registers
    v8s kpA, kpB, vpA, vpB;
    if (kt < 15) {
      const int jb = j0 + ((kt + 1) << 6);
      kpA = *(const v8s*)(Kb + (size_t)(jb + kr0)*64 + kc0);
      kpB = *(const v8s*)(Kb + (size_t)(jb + kr1)*64 + kc1);
      vpA = *(const v8s*)(Vb + (size_t)kr0*Sn + jb + kc0);
      vpB = *(const v8s*)(Vb + (size_t)kr1*Sn + jb + kc1);
    }

    // S^T = K Q^T : wave's keys = kh*32 + T*16 + (key subtiles T=0,1)
    v4f st[2][2];
    #pragma unroll
    for (int T = 0; T < 2; ++T) {
      const int rk = ((kh << 1) + T) << 1;    // region pair for this key subtile
      v8s ka0 = *(const v8s*)(KT + ((rk + 0) << 9) + (lane << 3));
      v8s ka1 = *(const v8s*)(KT + ((rk + 1) << 9) + (lane << 3));
      #pragma unroll
      for (int t = 0; t < 2; ++t) {
        v4f acc = (v4f){0.f,0.f,0.f,0.f};
        acc = MFMA16(ka0, qf[t][0], acc);
        acc = MFMA16(ka1, qf[t][1], acc);
        st[T][t] = acc;
      }
    }

    // p = 2^(s*SC): S^T C-layout -> lane holds P[q=l15][key=T*16+quad*4+r]
    // -> one contiguous b64 write per (T,t)
    #pragma unroll
    for (int t = 0; t < 2; ++t)
      #pragma unroll
      for (int T = 0; T < 2; ++T) {
        v4s pw;
        #pragma unroll
        for (int r = 0; r < 4; ++r) {
          const float pv = __builtin_amdgcn_exp2f(st[T][t][r]*SC);
          lsum[t] += pv;
          pw[r] = (short)f2bf_trunc(pv);
        }
        *(v4s*)(Pw + ((t << 4) + l15)*40 + (T << 4) + (quad << 2)) = pw;
      }

    __asm__ volatile("" ::: "memory");   // P reads strictly after P writes

    v8s ap[2];
    #pragma unroll
    for (int t = 0; t < 2; ++t)
      ap[t] = *(const v8s*)(Pw + ((t << 4) + l15)*40 + (quad << 3));

    // O += P V : V B-frags frag-major (region (n, kh))
    #pragma unroll
    for (int n = 0; n < 4; ++n) {
      v8s vb = *(const v8s*)(VT + (((n << 1) + kh) << 9) + (lane << 3));
      #pragma unroll
      for (int t = 0; t < 2; ++t)
        o_acc[t][n] = MFMA16(ap[t], vb, o_acc[t][n]);
    }

    __syncthreads();            // all waves done reading KT/VT
    if (kt < 15) {
      *(v8s*)(KT + (s0 << 3)) = kpA;
      *(v8s*)(KT + (s1 << 3)) = kpB;
      *(v8s*)(VT + (s0 << 3)) = vpA;
      *(v8s*)(VT + (s1 << 3)) = vpB;
    }
    __syncthreads();            // writeback visible
  }

  // reduce l across quads (lanes sharing l15)
  #pragma unroll
  for (int t = 0; t < 2; ++t) {
    lsum[t] += __shfl_xor(lsum[t], 16);
    lsum[t] += __shfl_xor(lsum[t], 32);
  }

  // write this (split, kh) partial: O [64 q][64 c] bf16, l [64 q] f32
  uint16_t* Ob = Opart + ((size_t)bx*2 + kh)*4096;
  float*    lp = lpart + ((size_t)bx*2 + kh)*64;
  #pragma unroll
  for (int t = 0; t < 2; ++t) {
    #pragma unroll
    for (int n = 0; n < 4; ++n)
      #pragma unroll
      for (int r = 0; r < 4; ++r)
        Ob[((qh << 5) + (t << 4) + (quad << 2) + r)*64 + (n << 4) + l15] = f2bf(o_acc[t][n][r]);
    if (quad == 0) lp[(qh << 5) + (t << 4) + l15] = lsum[t];
  }
}

// ---------------- kernel 4: merge 8 partials + projection + residual ---------
// grid 1024: bx = b*256 + st; s rows [st*16, +16). out[b][c][s] = x + Wp@A + bp
__global__ __launch_bounds__(256) void proj_res(
    const uint16_t* __restrict__ Opart, const float* __restrict__ lpart,
    const float* __restrict__ wp, const float* __restrict__ bp,
    const float* __restrict__ xg, float* __restrict__ out)
{
  __shared__ uint16_t As[16*68];   // merged attention subtile [s][c]
  const int tid  = threadIdx.x;
  const int w    = tid >> 6;
  const int lane = tid & 63;
  const int l15  = lane & 15;
  const int quad = lane >> 4;
  const int b      = blockIdx.x >> 8;
  const int st     = blockIdx.x & 255;
  const int qt     = st >> 2;
  const int sub    = st & 3;
  const int s_base = st << 4;

  const uint16_t* po = Opart + (size_t)((b*64 + qt)*8)*4096 + (sub << 4)*64;
  const float*    pl = lpart + ((b*64 + qt)*8)*64 + (sub << 4);

  { // merge 8 partials: thread t -> 4 elems, row = t>>4, col = (t&15)*4
    const int e = tid << 2, row = tid >> 4, col = (tid & 15) << 2;
    float lsum = 0.f;
    #pragma unroll
    for (int sp = 0; sp < 8; ++sp) lsum += pl[sp*64 + row];
    const float linv = 1.f / lsum;
    float acc[4] = {0.f,0.f,0.f,0.f};
    #pragma unroll
    for (int sp = 0; sp < 8; ++sp) {
      v4s o = *(const v4s*)(po + sp*4096 + e);
      #pragma unroll
      for (int j = 0; j < 4; ++j) acc[j] += bf2f((uint16_t)o[j]);
    }
    v4s a;
    #pragma unroll
    for (int j = 0; j < 4; ++j) a[j] = (short)f2bf(acc[j]*linv);
    *(v4s*)(As + row*68 + col) = a;
  }
  __syncthreads();

  v8s ba0 = *(const v8s*)(As + l15*68 + (quad << 3));
  v8s ba1 = *(const v8s*)(As + l15*68 + 32 + (quad << 3));

  // wave w computes output channels [w*16, +16)
  const float* Wr = wp + ((w << 4) + l15)*64 + (quad << 3);
  v8s a0 = pack8(*(const float4*)(Wr),      *(const float4*)(Wr + 4));
  v8s a1 = pack8(*(const float4*)(Wr + 32), *(const float4*)(Wr + 36));
  v4f d = (v4f){0.f,0.f,0.f,0.f};
  d = MFMA16(a0, ba0, d);
  d = MFMA16(a1, ba1, d);
  const int s = s_base + l15;
  #pragma unroll
  for (int r = 0; r < 4; ++r) {
    const int o = (w << 4) + (quad << 2) + r;
    const size_t idx = ((size_t)b*Cn + o)*Sn + s;
    out[idx] = d[r] + bp[o] + xg[idx];
  }
}

extern "C" void kernel_launch(void* const* d_in, const int* in_sizes, int n_in,
                              void* d_out, int out_size, void* d_ws, size_t ws_size,
                              hipStream_t stream)
{
  const float* x     = (const float*)d_in[0];
  const float* gamma = (const float*)d_in[1];
  const float* beta  = (const float*)d_in[2];
  const float* wq    = (const float*)d_in[3];
  const float* bq    = (const float*)d_in[4];
  const float* wk    = (const float*)d_in[5];
  const float* bk    = (const float*)d_in[6];
  const float* wv    = (const float*)d_in[7];
  const float* bv    = (const float*)d_in[8];
  const float* wp    = (const float*)d_in[9];
  const float* bp    = (const float*)d_in[10];

  float*    stats = (float*)d_ws;                        // 256 floats
  uint16_t* Qg    = (uint16_t*)d_ws + 1024;              // [B][S][C] bf16 (2 MiB)
  uint16_t* Kg    = Qg + (size_t)Bn*Sn*Cn;               // [B][S][C]
  uint16_t* Vg    = Kg + (size_t)Bn*Sn*Cn;               // [B][C][S]
  uint16_t* Opart = Vg + (size_t)Bn*Sn*Cn;               // 2048 x 64 x 64 bf16 (16 MiB)
  float*    lpart = (float*)(Opart + (size_t)2048*4096); // 2048 x 64 f32 (512 KiB)
  float*    outp  = (float*)d_out;

  gn_stats  <<<128, 256, 0, stream>>>(x, stats);
  gn_qkv    <<<1024, 256, 0, stream>>>(x, gamma, beta, wq, bq, wk, bk, wv, bv,
                                       stats, Qg, Kg, Vg);
  attn_split<<<1024, 256, 0, stream>>>(Qg, Kg, Vg, Opart, lpart);
  proj_res  <<<1024, 256, 0, stream>>>(Opart, lpart, wp, bp, x, outp);
}